// Round 1
// baseline (254.781 us; speedup 1.0000x reference)
//
#include <hip/hip_runtime.h>

// AdjGAT: V=20000 nodes, D=256 in-dim, K=16 neighbors, O=128 out-dim, H=4 heads.
// Pipeline:
//   K1 gemm_attn:      t[h][v][o] = sum_d x[v][d]*W[h][d][o]   (fp32 vector GEMM)
//                      attn[h][v] = sum_o t[h][v][o]*a[h][o]    (fused epilogue)
//   K2 gather_softmax: per v: softmax over K neighbor logits per head (pad-masked),
//                      out[v][o] = relu( mean_h( sum_k coef*t[h][nbr][o] + b[h][o] ) )
// Workspace: t = H*V*O fp32 (40.96 MB) + attn = H*V fp32 (0.32 MB) in d_ws.

#define V_N 20000
#define D_N 256
#define K_N 16
#define O_N 128
#define H_N 4
#define NEG_INF -1e9f

// ---------------- Kernel 1: per-head GEMM + attention-logit epilogue ----------------
// Tile: BM=128 rows x BN=128 cols (BN == O), BK=16, 256 threads, 8x8 micro-tile.
// rows: ty + i*16 (ty=tid>>4, i<8); cols: tx + j*16 (tx=tid&15, j<8).
// LDS reads: xs broadcast across tx (conflict-free), ws consecutive across tx
// (conflict-free); 16 scalar ds_reads per 64 FMAs.
__global__ __launch_bounds__(256) void gemm_attn_kernel(
    const float* __restrict__ x, const float* __restrict__ W,
    const float* __restrict__ a, float* __restrict__ t, float* __restrict__ attn)
{
    const int h   = blockIdx.y;
    const int m0  = blockIdx.x * 128;
    const int tid = threadIdx.x;
    const int tx  = tid & 15;
    const int ty  = tid >> 4;

    __shared__ float xs[128][17];   // [row][k], +1 pad breaks row-stride conflicts
    __shared__ float ws[16][128];   // [k][col]

    float acc[8][8];
    #pragma unroll
    for (int i = 0; i < 8; ++i)
        #pragma unroll
        for (int j = 0; j < 8; ++j) acc[i][j] = 0.f;

    const float* Wh = W + (size_t)h * D_N * O_N;

    for (int kc = 0; kc < D_N; kc += 16) {
        // stage x tile: 128 rows x 16 cols; 8 floats (2x float4) per thread
        {
            const int lr = tid >> 1;          // 0..127
            const int lc = (tid & 1) * 8;     // 0 or 8
            const int v  = m0 + lr;
            if (v < V_N) {
                const float* src = x + (size_t)v * D_N + kc + lc;
                float4 p0 = *(const float4*)(src);
                float4 p1 = *(const float4*)(src + 4);
                xs[lr][lc+0]=p0.x; xs[lr][lc+1]=p0.y; xs[lr][lc+2]=p0.z; xs[lr][lc+3]=p0.w;
                xs[lr][lc+4]=p1.x; xs[lr][lc+5]=p1.y; xs[lr][lc+6]=p1.z; xs[lr][lc+7]=p1.w;
            } else {
                #pragma unroll
                for (int q = 0; q < 8; ++q) xs[lr][lc+q] = 0.f;
            }
        }
        // stage W tile: 16 rows x 128 cols; 8 floats per thread, fully coalesced
        {
            const int wr = tid >> 4;          // 0..15
            const int wc = (tid & 15) * 8;    // 0..120
            const float* src = Wh + (size_t)(kc + wr) * O_N + wc;
            *(float4*)&ws[wr][wc]     = *(const float4*)(src);
            *(float4*)&ws[wr][wc + 4] = *(const float4*)(src + 4);
        }
        __syncthreads();

        #pragma unroll
        for (int kk = 0; kk < 16; ++kk) {
            float xf[8], wf[8];
            #pragma unroll
            for (int i = 0; i < 8; ++i) xf[i] = xs[ty + i*16][kk];
            #pragma unroll
            for (int j = 0; j < 8; ++j) wf[j] = ws[kk][tx + j*16];
            #pragma unroll
            for (int i = 0; i < 8; ++i)
                #pragma unroll
                for (int j = 0; j < 8; ++j)
                    acc[i][j] = fmaf(xf[i], wf[j], acc[i][j]);
        }
        __syncthreads();
    }

    // attention vector for this head at our 8 columns
    float av[8];
    #pragma unroll
    for (int j = 0; j < 8; ++j) av[j] = a[h * O_N + tx + j*16];

    // epilogue: store t, fused attn = t . a  (width-16 shuffle reduce over tx)
    #pragma unroll
    for (int i = 0; i < 8; ++i) {
        const int v = m0 + ty + i*16;     // uniform across the 16-lane tx group
        float part = 0.f;
        if (v < V_N) {
            float* dst = t + ((size_t)h * V_N + v) * O_N;
            #pragma unroll
            for (int j = 0; j < 8; ++j) {
                dst[tx + j*16] = acc[i][j];
                part = fmaf(acc[i][j], av[j], part);
            }
        }
        #pragma unroll
        for (int s = 8; s >= 1; s >>= 1)
            part += __shfl_xor(part, s, 16);
        if (tx == 0 && v < V_N) attn[h * V_N + v] = part;
    }
}

// ---------------- Kernel 2: neighbor softmax + weighted gather ----------------
// One block per node v; 128 threads (thread == output channel o).
__global__ __launch_bounds__(128) void gather_softmax_kernel(
    const float* __restrict__ t, const float* __restrict__ attn,
    const float* __restrict__ b, const int* __restrict__ adj,
    const int* __restrict__ mask_p, float* __restrict__ out)
{
    const int v   = blockIdx.x;
    const int tid = threadIdx.x;

    __shared__ float coefs[H_N][K_N];
    __shared__ int   sidx[K_N];

    if (tid < 64) {                       // wave 0: 4 head-groups of 16 lanes
        const int h = tid >> 4;
        const int k = tid & 15;
        const int mask = mask_p[0];
        const int idx  = adj[v * K_N + k];
        const bool pad = (idx >= mask);   // only == mask occurs; >= is the safe clip
        const int safe = pad ? 0 : idx;
        float logit = pad ? NEG_INF : attn[h * V_N + safe];
        // width-16 max
        float m = logit;
        #pragma unroll
        for (int s = 8; s >= 1; s >>= 1)
            m = fmaxf(m, __shfl_xor(m, s, 16));
        float e = pad ? 0.f : __expf(logit - m);
        float sum = e;
        #pragma unroll
        for (int s = 8; s >= 1; s >>= 1)
            sum += __shfl_xor(sum, s, 16);
        // pad coef forced to 0: matches reference (exp(-1e9-m)==0), and in the
        // measure-zero all-pad case avoids 0/0 while still giving head = b.
        coefs[h][k] = pad ? 0.f : e / sum;
        if (h == 0) sidx[k] = safe;
    }
    __syncthreads();

    const int o = tid;                    // 0..127
    float bm = 0.f;
    #pragma unroll
    for (int h = 0; h < H_N; ++h) bm += b[h * O_N + o];
    bm *= (1.0f / H_N);

    float acc = 0.f;
    #pragma unroll
    for (int h = 0; h < H_N; ++h) {
        const float* th = t + (size_t)h * V_N * O_N;
        #pragma unroll
        for (int k = 0; k < K_N; ++k)
            acc = fmaf(coefs[h][k], th[(size_t)sidx[k] * O_N + o], acc);
    }
    const float r = acc * (1.0f / H_N) + bm;
    out[v * O_N + o] = r > 0.f ? r : 0.f;
}

extern "C" void kernel_launch(void* const* d_in, const int* in_sizes, int n_in,
                              void* d_out, int out_size, void* d_ws, size_t ws_size,
                              hipStream_t stream) {
    const float* x      = (const float*)d_in[0];
    const float* W      = (const float*)d_in[1];
    const float* a      = (const float*)d_in[2];
    const float* b      = (const float*)d_in[3];
    const int*   adj    = (const int*)d_in[4];
    const int*   mask_p = (const int*)d_in[5];
    float*       out    = (float*)d_out;

    // workspace layout: t [H][V][O] fp32, then attn [H][V] fp32 (~41.3 MB total)
    float* t    = (float*)d_ws;
    float* attn = (float*)((char*)d_ws + (size_t)H_N * V_N * O_N * sizeof(float));

    dim3 g1((V_N + 127) / 128, H_N);
    gemm_attn_kernel<<<g1, 256, 0, stream>>>(x, W, a, t, attn);
    gather_softmax_kernel<<<V_N, 128, 0, stream>>>(t, attn, b, adj, mask_p, out);
}

// Round 2
// 164.506 us; speedup vs baseline: 1.5488x; 1.5488x over previous
//
#include <hip/hip_runtime.h>
#include <hip/hip_bf16.h>

// AdjGAT: V=20000, D=256, K=16, O=128, H=4.
// Pipeline (all fp32 inputs):
//   K0 prep_w:       W[h][d][o] fp32 -> Wt_hi/Wt_lo[h][o][d] bf16 (split, transposed)
//   K1 gemm_attn:    t[h][v][o] = sum_d x*W via split-bf16 MFMA (3 terms ~ fp32 acc);
//                    t stored bf16; attn[h][v] = t.a fused from fp32 accumulators.
//   K2 gather:       per-v softmax over K neighbor logits (pad-masked), weighted
//                    bf16 gather of t, mean over heads, +b, relu.
// ws: t bf16 (20.48MB) | attn fp32 (0.32MB) | Wt_hi (256KB) | Wt_lo (256KB)

#define V_N 20000
#define D_N 256
#define K_N 16
#define O_N 128
#define H_N 4
#define NEG_INF -1e9f
#define BM 32            // rows per block in K1
#define LDK 264          // padded LDS k-stride (bf16 elems): 528B = 33*16B, 2-way banks

typedef short  bf16x8 __attribute__((ext_vector_type(8)));
typedef short  bf16x4 __attribute__((ext_vector_type(4)));
typedef float  f32x4  __attribute__((ext_vector_type(4)));

__device__ __forceinline__ short f2bf(float f) {
    __hip_bfloat16 h = __float2bfloat16(f);   // RNE
    return *reinterpret_cast<short*>(&h);
}
__device__ __forceinline__ float bf2f(short s) {
    __hip_bfloat16 h = *reinterpret_cast<__hip_bfloat16*>(&s);
    return __bfloat162float(h);
}

// ---------------- K0: split + transpose W into ws ----------------
// idx enumerates Wt layout [h][o][d]; writes coalesced, reads strided (L2-served).
__global__ __launch_bounds__(256) void prep_w_kernel(
    const float* __restrict__ W, short* __restrict__ Wt_hi, short* __restrict__ Wt_lo)
{
    const int idx = blockIdx.x * 256 + threadIdx.x;   // 0 .. H*O*D-1 = 131071
    const int d    = idx & (D_N - 1);
    const int rest = idx >> 8;            // h*O + o
    const int o    = rest & (O_N - 1);
    const int h    = rest >> 7;
    const float f  = W[((size_t)(h * D_N + d)) * O_N + o];
    const short hi = f2bf(f);
    const short lo = f2bf(f - bf2f(hi));
    Wt_hi[idx] = hi;
    Wt_lo[idx] = lo;
}

// ---------------- K1: split-bf16 MFMA GEMM + fused attn ----------------
// 625 blocks x 256 threads (4 waves). Wave w computes head h=w for rows
// [m0, m0+32). x slab staged once in LDS as hi/lo bf16 (padded stride LDK).
// B-fragments (16B, k-contiguous) loaded directly from Wt in global (L2-hot).
// MFMA 16x16x32_bf16: A[m=lane&15][k=(lane>>4)*8+j], B[n=lane&15][k=...],
// C[row=(lane>>4)*4+reg][col=lane&15]  (verified layouts, learn_hip m89/m91).
__global__ __launch_bounds__(256, 2) void gemm_attn_kernel(
    const float* __restrict__ x, const short* __restrict__ Wt_hi,
    const short* __restrict__ Wt_lo, const float* __restrict__ a,
    __hip_bfloat16* __restrict__ t, float* __restrict__ attn)
{
    const int m0  = blockIdx.x * BM;
    const int tid = threadIdx.x;

    __shared__ short xs_hi[BM * LDK];
    __shared__ short xs_lo[BM * LDK];

    // ---- stage x slab [32][256] fp32 -> hi/lo bf16 in LDS ----
    #pragma unroll
    for (int it = 0; it < 8; ++it) {
        const int idx = it * 256 + tid;       // 0..2047
        const int row = idx >> 6;             // 0..31
        const int c4  = (idx & 63) * 4;       // 0..252
        const float4 p = *(const float4*)&x[(size_t)(m0 + row) * D_N + c4];
        short h0 = f2bf(p.x), h1 = f2bf(p.y), h2 = f2bf(p.z), h3 = f2bf(p.w);
        bf16x4 vh = { h0, h1, h2, h3 };
        bf16x4 vl = { f2bf(p.x - bf2f(h0)), f2bf(p.y - bf2f(h1)),
                      f2bf(p.z - bf2f(h2)), f2bf(p.w - bf2f(h3)) };
        *(bf16x4*)&xs_hi[row * LDK + c4] = vh;
        *(bf16x4*)&xs_lo[row * LDK + c4] = vl;
    }
    __syncthreads();

    const int h    = tid >> 6;        // wave id == head
    const int lane = tid & 63;
    const int lo4  = lane & 15;
    const int q    = lane >> 4;

    const short* __restrict__ Bh = Wt_hi + (size_t)h * O_N * D_N;
    const short* __restrict__ Bl = Wt_lo + (size_t)h * O_N * D_N;

    f32x4 acc[2][8];
    #pragma unroll
    for (int mt = 0; mt < 2; ++mt)
        #pragma unroll
        for (int nt = 0; nt < 8; ++nt) acc[mt][nt] = (f32x4){0.f, 0.f, 0.f, 0.f};

    #pragma unroll
    for (int kc = 0; kc < D_N; kc += 32) {
        bf16x8 a_hi[2], a_lo[2];
        #pragma unroll
        for (int mt = 0; mt < 2; ++mt) {
            const int off = (mt * 16 + lo4) * LDK + kc + q * 8;
            a_hi[mt] = *(const bf16x8*)&xs_hi[off];
            a_lo[mt] = *(const bf16x8*)&xs_lo[off];
        }
        #pragma unroll
        for (int nt = 0; nt < 8; ++nt) {
            const size_t boff = (size_t)(nt * 16 + lo4) * D_N + kc + q * 8;
            const bf16x8 b_hi = *(const bf16x8*)&Bh[boff];
            const bf16x8 b_lo = *(const bf16x8*)&Bl[boff];
            #pragma unroll
            for (int mt = 0; mt < 2; ++mt) {
                acc[mt][nt] = __builtin_amdgcn_mfma_f32_16x16x32_bf16(
                    a_hi[mt], b_hi, acc[mt][nt], 0, 0, 0);
                acc[mt][nt] = __builtin_amdgcn_mfma_f32_16x16x32_bf16(
                    a_lo[mt], b_hi, acc[mt][nt], 0, 0, 0);
                acc[mt][nt] = __builtin_amdgcn_mfma_f32_16x16x32_bf16(
                    a_hi[mt], b_lo, acc[mt][nt], 0, 0, 0);
            }
        }
    }

    // ---- epilogue: t (bf16) store + fused attn = t . a ----
    float av[8];
    #pragma unroll
    for (int nt = 0; nt < 8; ++nt) av[nt] = a[h * O_N + nt * 16 + lo4];

    #pragma unroll
    for (int mt = 0; mt < 2; ++mt) {
        float part[4] = {0.f, 0.f, 0.f, 0.f};
        #pragma unroll
        for (int nt = 0; nt < 8; ++nt) {
            #pragma unroll
            for (int r = 0; r < 4; ++r) {
                const float val = acc[mt][nt][r];
                const int v = m0 + mt * 16 + q * 4 + r;
                t[((size_t)h * V_N + v) * O_N + nt * 16 + lo4] = __float2bfloat16(val);
                part[r] = fmaf(val, av[nt], part[r]);
            }
        }
        #pragma unroll
        for (int r = 0; r < 4; ++r) {
            float s = part[r];
            #pragma unroll
            for (int d = 8; d >= 1; d >>= 1) s += __shfl_xor(s, d);
            if (lo4 == 0) {
                const int v = m0 + mt * 16 + q * 4 + r;
                attn[h * V_N + v] = s;
            }
        }
    }
}

// ---------------- K2: neighbor softmax + weighted bf16 gather ----------------
__global__ __launch_bounds__(128) void gather_softmax_kernel(
    const __hip_bfloat16* __restrict__ t, const float* __restrict__ attn,
    const float* __restrict__ b, const int* __restrict__ adj,
    const int* __restrict__ mask_p, float* __restrict__ out)
{
    const int v   = blockIdx.x;
    const int tid = threadIdx.x;

    __shared__ float coefs[H_N][K_N];
    __shared__ int   sidx[K_N];

    if (tid < 64) {                       // wave 0: 4 head-groups of 16 lanes
        const int h = tid >> 4;
        const int k = tid & 15;
        const int mask = mask_p[0];
        const int idx  = adj[v * K_N + k];
        const bool pad = (idx >= mask);
        const int safe = pad ? 0 : idx;
        float logit = pad ? NEG_INF : attn[h * V_N + safe];
        float m = logit;
        #pragma unroll
        for (int s = 8; s >= 1; s >>= 1)
            m = fmaxf(m, __shfl_xor(m, s, 16));
        float e = pad ? 0.f : __expf(logit - m);
        float sum = e;
        #pragma unroll
        for (int s = 8; s >= 1; s >>= 1)
            sum += __shfl_xor(sum, s, 16);
        // pad coef 0: matches exp(-1e9-m)==0; all-pad case -> head = b (ref-equal).
        coefs[h][k] = pad ? 0.f : e / sum;
        if (h == 0) sidx[k] = safe;
    }
    __syncthreads();

    const int o = tid;                    // 0..127
    float bm = 0.f;
    #pragma unroll
    for (int h = 0; h < H_N; ++h) bm += b[h * O_N + o];
    bm *= (1.0f / H_N);

    float acc = 0.f;
    #pragma unroll
    for (int h = 0; h < H_N; ++h) {
        const __hip_bfloat16* th = t + (size_t)h * V_N * O_N;
        #pragma unroll
        for (int k = 0; k < K_N; ++k)
            acc = fmaf(coefs[h][k],
                       __bfloat162float(th[(size_t)sidx[k] * O_N + o]), acc);
    }
    const float r = acc * (1.0f / H_N) + bm;
    out[v * O_N + o] = r > 0.f ? r : 0.f;
}

extern "C" void kernel_launch(void* const* d_in, const int* in_sizes, int n_in,
                              void* d_out, int out_size, void* d_ws, size_t ws_size,
                              hipStream_t stream) {
    const float* x      = (const float*)d_in[0];
    const float* W      = (const float*)d_in[1];
    const float* a      = (const float*)d_in[2];
    const float* b      = (const float*)d_in[3];
    const int*   adj    = (const int*)d_in[4];
    const int*   mask_p = (const int*)d_in[5];
    float*       out    = (float*)d_out;

    // ws layout
    char* p = (char*)d_ws;
    __hip_bfloat16* t    = (__hip_bfloat16*)p;                 // H*V*O bf16 = 20,480,000 B
    float*          attn = (float*)(p + 20480000);             // H*V fp32  = 320,000 B
    short*          Wthi = (short*)(p + 20800000);             // 262,144 B
    short*          Wtlo = (short*)(p + 21062144);             // 262,144 B

    prep_w_kernel<<<(H_N * O_N * D_N) / 256, 256, 0, stream>>>(W, Wthi, Wtlo);
    gemm_attn_kernel<<<V_N / BM, 256, 0, stream>>>(x, Wthi, Wtlo, a, t, attn);
    gather_softmax_kernel<<<V_N, 128, 0, stream>>>(t, attn, b, adj, mask_p, out);
}

// Round 3
// 148.607 us; speedup vs baseline: 1.7145x; 1.1070x over previous
//
#include <hip/hip_runtime.h>
#include <hip/hip_bf16.h>

// AdjGAT: V=20000, D=256, K=16, O=128, H=4.
// Pipeline:
//   K0a prep_w: W[h][d][o] fp32 -> Wt_hi/Wt_lo[h][o][d] bf16 (split, transposed)
//   K0b prep_x: x[v][d] fp32   -> x_hi/x_lo[v][d] bf16 (split)
//   K1  gemm_attn: per-head 160x128-tile MFMA GEMM, A/B staged via async
//       global_load_lds (width 16), 3-term split-bf16 (~fp32 accuracy);
//       t stored bf16, attn fused from fp32 accumulators.
//   K2  gather: per-v softmax over K neighbor logits (pad-masked), vectorized
//       bf16x4 gather of t, mean over heads, +b, relu.
// ws: t bf16 20.48MB | attn f32 0.32MB | Wt 0.52MB | x_hi/x_lo 20.48MB  (~41.8MB)

#define V_N 20000
#define D_N 256
#define K_N 16
#define O_N 128
#define H_N 4
#define NEG_INF -1e9f
#define BM 160           // V = 125 * 160 exactly -> no edge guards

typedef short  bf16x8 __attribute__((ext_vector_type(8)));
typedef short  bf16x4 __attribute__((ext_vector_type(4)));
typedef float  f32x4  __attribute__((ext_vector_type(4)));

__device__ __forceinline__ short f2bf(float f) {
    __hip_bfloat16 h = __float2bfloat16(f);   // RNE
    return *reinterpret_cast<short*>(&h);
}
__device__ __forceinline__ float bf2f(short s) {
    __hip_bfloat16 h = *reinterpret_cast<__hip_bfloat16*>(&s);
    return __bfloat162float(h);
}

// async global->LDS, 16B per lane; lds must be wave-uniform, gets +lane*16.
__device__ __forceinline__ void async16(void* lds, const void* g) {
    __builtin_amdgcn_global_load_lds(
        (const __attribute__((address_space(1))) void*)g,
        (__attribute__((address_space(3))) void*)lds, 16, 0, 0);
}

// ---------------- K0a: split + transpose W ----------------
__global__ __launch_bounds__(256) void prep_w_kernel(
    const float* __restrict__ W, short* __restrict__ Wt_hi, short* __restrict__ Wt_lo)
{
    const int idx = blockIdx.x * 256 + threadIdx.x;   // [h][o][d] order
    const int d    = idx & (D_N - 1);
    const int rest = idx >> 8;
    const int o    = rest & (O_N - 1);
    const int h    = rest >> 7;
    const float f  = W[((size_t)(h * D_N + d)) * O_N + o];
    const short hi = f2bf(f);
    const short lo = f2bf(f - bf2f(hi));
    Wt_hi[idx] = hi;
    Wt_lo[idx] = lo;
}

// ---------------- K0b: split x ----------------
__global__ __launch_bounds__(256) void prep_x_kernel(
    const float* __restrict__ x, short* __restrict__ x_hi, short* __restrict__ x_lo)
{
    const int idx = blockIdx.x * 256 + threadIdx.x;   // one float4 per thread
    const float4 p = *(const float4*)&x[(size_t)idx * 4];
    short h0 = f2bf(p.x), h1 = f2bf(p.y), h2 = f2bf(p.z), h3 = f2bf(p.w);
    bf16x4 vh = { h0, h1, h2, h3 };
    bf16x4 vl = { f2bf(p.x - bf2f(h0)), f2bf(p.y - bf2f(h1)),
                  f2bf(p.z - bf2f(h2)), f2bf(p.w - bf2f(h3)) };
    *(bf16x4*)&x_hi[(size_t)idx * 4] = vh;
    *(bf16x4*)&x_lo[(size_t)idx * 4] = vl;
}

// ---------------- K1: async-staged split-bf16 MFMA GEMM + fused attn ----------
// grid (125, 4heads) x 256 thr (4 waves, 2x2): wave = 80 rows x 64 cols.
// LDS tiles (K=32 slice): A 160x32, B 128x32, hi+lo; rows are 64B contiguous ->
// global_load_lds covers 16 rows per instr; ds_read_b128 frags conflict-free.
__global__ __launch_bounds__(256, 2) void gemm_attn_kernel(
    const short* __restrict__ x_hi, const short* __restrict__ x_lo,
    const short* __restrict__ Wt_hi, const short* __restrict__ Wt_lo,
    const float* __restrict__ a, __hip_bfloat16* __restrict__ t,
    float* __restrict__ attn)
{
    const int m0   = blockIdx.x * BM;
    const int h    = blockIdx.y;
    const int tid  = threadIdx.x;
    const int wid  = tid >> 6;
    const int lane = tid & 63;
    const int lo4  = lane & 15;
    const int q    = lane >> 4;
    const int wave_m = wid & 1;      // row half: 80 rows
    const int wave_n = wid >> 1;     // col half: 64 cols

    __shared__ short As_hi[BM * 32];
    __shared__ short As_lo[BM * 32];
    __shared__ short Bs_hi[O_N * 32];
    __shared__ short Bs_lo[O_N * 32];
    __shared__ float attn_s[2][BM];

    const short* __restrict__ Bh = Wt_hi + (size_t)h * O_N * D_N;
    const short* __restrict__ Bl = Wt_lo + (size_t)h * O_N * D_N;

    f32x4 acc[5][4];
    #pragma unroll
    for (int mt = 0; mt < 5; ++mt)
        #pragma unroll
        for (int nt = 0; nt < 4; ++nt) acc[mt][nt] = (f32x4){0.f, 0.f, 0.f, 0.f};

    const int srow = lane >> 2;          // 0..15 row within 16-row chunk
    const int scol = (lane & 3) * 8;     // 0/8/16/24 shorts = 16B steps

    for (int kc = 0; kc < D_N; kc += 32) {
        // ---- async stage: wave w fills one array ----
        if (wid == 0) {
            #pragma unroll
            for (int i = 0; i < 10; ++i)
                async16(&As_hi[i * 512],
                        &x_hi[(size_t)(m0 + i * 16 + srow) * D_N + kc + scol]);
        } else if (wid == 1) {
            #pragma unroll
            for (int i = 0; i < 10; ++i)
                async16(&As_lo[i * 512],
                        &x_lo[(size_t)(m0 + i * 16 + srow) * D_N + kc + scol]);
        } else if (wid == 2) {
            #pragma unroll
            for (int i = 0; i < 8; ++i)
                async16(&Bs_hi[i * 512],
                        &Bh[(size_t)(i * 16 + srow) * D_N + kc + scol]);
        } else {
            #pragma unroll
            for (int i = 0; i < 8; ++i)
                async16(&Bs_lo[i * 512],
                        &Bl[(size_t)(i * 16 + srow) * D_N + kc + scol]);
        }
        __syncthreads();

        // ---- fragments ----
        bf16x8 ah[5], al[5], bh[4], bl[4];
        #pragma unroll
        for (int mt = 0; mt < 5; ++mt) {
            const int off = (wave_m * 80 + mt * 16 + lo4) * 32 + q * 8;
            ah[mt] = *(const bf16x8*)&As_hi[off];
            al[mt] = *(const bf16x8*)&As_lo[off];
        }
        #pragma unroll
        for (int nt = 0; nt < 4; ++nt) {
            const int off = (wave_n * 64 + nt * 16 + lo4) * 32 + q * 8;
            bh[nt] = *(const bf16x8*)&Bs_hi[off];
            bl[nt] = *(const bf16x8*)&Bs_lo[off];
        }
        #pragma unroll
        for (int nt = 0; nt < 4; ++nt)
            #pragma unroll
            for (int mt = 0; mt < 5; ++mt) {
                acc[mt][nt] = __builtin_amdgcn_mfma_f32_16x16x32_bf16(
                    ah[mt], bh[nt], acc[mt][nt], 0, 0, 0);
                acc[mt][nt] = __builtin_amdgcn_mfma_f32_16x16x32_bf16(
                    al[mt], bh[nt], acc[mt][nt], 0, 0, 0);
                acc[mt][nt] = __builtin_amdgcn_mfma_f32_16x16x32_bf16(
                    ah[mt], bl[nt], acc[mt][nt], 0, 0, 0);
            }
        __syncthreads();
    }

    // ---- epilogue: t (bf16) + fused attn ----
    float av[4];
    #pragma unroll
    for (int nt = 0; nt < 4; ++nt)
        av[nt] = a[h * O_N + wave_n * 64 + nt * 16 + lo4];

    #pragma unroll
    for (int mt = 0; mt < 5; ++mt) {
        float part[4] = {0.f, 0.f, 0.f, 0.f};
        #pragma unroll
        for (int nt = 0; nt < 4; ++nt) {
            #pragma unroll
            for (int r = 0; r < 4; ++r) {
                const float val = acc[mt][nt][r];
                const int v   = m0 + wave_m * 80 + mt * 16 + q * 4 + r;
                const int col = wave_n * 64 + nt * 16 + lo4;
                t[((size_t)h * V_N + v) * O_N + col] = __float2bfloat16(val);
                part[r] = fmaf(val, av[nt], part[r]);
            }
        }
        #pragma unroll
        for (int r = 0; r < 4; ++r) {
            float s = part[r];
            #pragma unroll
            for (int d = 8; d >= 1; d >>= 1) s += __shfl_xor(s, d);  // over lo4
            if (lo4 == 0)
                attn_s[wave_n][wave_m * 80 + mt * 16 + q * 4 + r] = s;
        }
    }
    __syncthreads();
    if (tid < BM)
        attn[h * V_N + m0 + tid] = attn_s[0][tid] + attn_s[1][tid];
}

// ---------------- K2: softmax + vectorized weighted gather ----------------
// 128 thr: thread = (head h = tid>>5, o-group og = tid&31 -> 4 channels).
// 16 x 8B loads per thread; cross-head reduce via shfl_xor(32) + LDS.
__global__ __launch_bounds__(128) void gather_softmax_kernel(
    const __hip_bfloat16* __restrict__ t, const float* __restrict__ attn,
    const float* __restrict__ b, const int* __restrict__ adj,
    const int* __restrict__ mask_p, float* __restrict__ out)
{
    const int v   = blockIdx.x;
    const int tid = threadIdx.x;

    __shared__ float coefs[H_N][K_N];
    __shared__ int   sidx[K_N];
    __shared__ float red[32][4];

    if (tid < 64) {                       // wave 0: 4 head-groups of 16 lanes
        const int hh = tid >> 4;
        const int k  = tid & 15;
        const int mask = mask_p[0];
        const int idx  = adj[v * K_N + k];
        const bool pad = (idx >= mask);
        const int safe = pad ? 0 : idx;
        float logit = pad ? NEG_INF : attn[hh * V_N + safe];
        float m = logit;
        #pragma unroll
        for (int s = 8; s >= 1; s >>= 1)
            m = fmaxf(m, __shfl_xor(m, s, 16));
        float e = pad ? 0.f : __expf(logit - m);
        float sum = e;
        #pragma unroll
        for (int s = 8; s >= 1; s >>= 1)
            sum += __shfl_xor(sum, s, 16);
        // pad coef 0 == ref (exp(-1e9-m)==0); all-pad -> features zeroed anyway.
        coefs[hh][k] = pad ? 0.f : e / sum;
        if (hh == 0) sidx[k] = safe;
    }
    __syncthreads();

    const int h  = tid >> 5;              // 0..3
    const int og = tid & 31;              // 4-channel group
    const __hip_bfloat16* th = t + (size_t)h * V_N * O_N + og * 4;

    float a0 = 0.f, a1 = 0.f, a2 = 0.f, a3 = 0.f;
    #pragma unroll
    for (int k = 0; k < K_N; ++k) {
        const float c = coefs[h][k];
        const bf16x4 w = *(const bf16x4*)(th + (size_t)sidx[k] * O_N);
        a0 = fmaf(c, bf2f(w[0]), a0);
        a1 = fmaf(c, bf2f(w[1]), a1);
        a2 = fmaf(c, bf2f(w[2]), a2);
        a3 = fmaf(c, bf2f(w[3]), a3);
    }
    // combine head pairs within each wave (lanes l <-> l^32)
    a0 += __shfl_xor(a0, 32);
    a1 += __shfl_xor(a1, 32);
    a2 += __shfl_xor(a2, 32);
    a3 += __shfl_xor(a3, 32);
    if (tid >= 64 && tid < 96) {          // wave1 lower half: h2+h3 sums
        red[og][0] = a0; red[og][1] = a1; red[og][2] = a2; red[og][3] = a3;
    }
    __syncthreads();
    if (tid < 32) {                       // wave0 lower half: h0+h1 sums
        float4 o4;
        float bm[4];
        #pragma unroll
        for (int j = 0; j < 4; ++j) {
            float s = 0.f;
            #pragma unroll
            for (int hh = 0; hh < H_N; ++hh) s += b[hh * O_N + og * 4 + j];
            bm[j] = s * 0.25f;
        }
        o4.x = fmaxf((a0 + red[og][0]) * 0.25f + bm[0], 0.f);
        o4.y = fmaxf((a1 + red[og][1]) * 0.25f + bm[1], 0.f);
        o4.z = fmaxf((a2 + red[og][2]) * 0.25f + bm[2], 0.f);
        o4.w = fmaxf((a3 + red[og][3]) * 0.25f + bm[3], 0.f);
        *(float4*)&out[(size_t)v * O_N + og * 4] = o4;
    }
}

extern "C" void kernel_launch(void* const* d_in, const int* in_sizes, int n_in,
                              void* d_out, int out_size, void* d_ws, size_t ws_size,
                              hipStream_t stream) {
    const float* x      = (const float*)d_in[0];
    const float* W      = (const float*)d_in[1];
    const float* a      = (const float*)d_in[2];
    const float* b      = (const float*)d_in[3];
    const int*   adj    = (const int*)d_in[4];
    const int*   mask_p = (const int*)d_in[5];
    float*       out    = (float*)d_out;

    // ws layout (bytes):
    char* p = (char*)d_ws;
    __hip_bfloat16* t    = (__hip_bfloat16*)p;            // 20,480,000
    float*          attn = (float*)(p + 20480000);        //    320,000
    short*          Wthi = (short*)(p + 20800000);        //    262,144
    short*          Wtlo = (short*)(p + 21062144);        //    262,144
    short*          xhi  = (short*)(p + 21324288);        // 10,240,000
    short*          xlo  = (short*)(p + 31564288);        // 10,240,000  (end 41.8MB)

    prep_w_kernel<<<(H_N * O_N * D_N) / 256, 256, 0, stream>>>(W, Wthi, Wtlo);
    prep_x_kernel<<<(V_N * D_N / 4) / 256, 256, 0, stream>>>(x, xhi, xlo);
    dim3 g1(V_N / BM, H_N);
    gemm_attn_kernel<<<g1, 256, 0, stream>>>(xhi, xlo, Wthi, Wtlo, a, t, attn);
    gather_softmax_kernel<<<V_N, 128, 0, stream>>>(t, attn, b, adj, mask_p, out);
}